// Round 1
// 616.239 us; speedup vs baseline: 1.0122x; 1.0122x over previous
//
#include <hip/hip_runtime.h>
#include <math.h>

#define DIM 2400
#define VEC (DIM / 4)      // 600 float4 per row
#define FULL_K 9           // k = 0..8: w = k*64 + lane <= 575 < 600, all lanes valid
#define TAIL_LANES 24      // k = 9: w = 576 + lane, valid for lane < 24
#define EPS 1e-6f
#define MARGIN 1.0f
#define NPOS 5

// ---------------------------------------------------------------------------
// Kernel 1: d_ap[p] = ||anchor - pos[p] + EPS||_2, p in [0,5). One wave per
// positive row. Also zeroes the output accumulator. Negligible cost (~60 KB).
// ---------------------------------------------------------------------------
__global__ void dap_kernel(const float* __restrict__ anchor,
                           const float* __restrict__ pos,
                           float* __restrict__ dap,
                           float* __restrict__ out) {
    const int lane = threadIdx.x & 63;
    const int wave = threadIdx.x >> 6;          // 0..4
    const float4* a4 = (const float4*)anchor;
    const float4* p4 = (const float4*)(pos + wave * DIM);

    float acc = 0.0f;
    for (int w = lane; w < VEC; w += 64) {
        float4 a = a4[w];
        float4 b = p4[w];
        float dx = a.x - b.x + EPS;
        float dy = a.y - b.y + EPS;
        float dz = a.z - b.z + EPS;
        float dw = a.w - b.w + EPS;
        acc = fmaf(dx, dx, fmaf(dy, dy, fmaf(dz, dz, fmaf(dw, dw, acc))));
    }
    #pragma unroll
    for (int off = 32; off > 0; off >>= 1)
        acc += __shfl_down(acc, off, 64);
    if (lane == 0) dap[wave] = sqrtf(acc);
    if (threadIdx.x == 0) *out = 0.0f;
}

// ---------------------------------------------------------------------------
// Kernel 2: one wave per negative row, grid-stride over rows.
//   loss += relu(d_ap[row % 5] - ||anchor - neg[row] + EPS|| + MARGIN)
// Anchor (pre-biased by EPS) lives in VGPRs: lane holds float4 slices
// k*64+lane, k = 0..9. Inner loop fully unrolled and branch-free for k<9 so
// all 9-10 global_load_dwordx4 issue before any s_waitcnt (max MLP).
// 4 independent accumulators break the serial FMA chain.
// ---------------------------------------------------------------------------
__global__ __launch_bounds__(256, 4)
void triplet_kernel(const float* __restrict__ anchor,
                    const float* __restrict__ neg,
                    const float* __restrict__ dap,
                    float* __restrict__ out,
                    int n_rows) {
    __shared__ float s_dap[NPOS];
    __shared__ float s_partial[4];

    const int lane = threadIdx.x & 63;
    const int wave = threadIdx.x >> 6;

    if (threadIdx.x < NPOS) s_dap[threadIdx.x] = dap[threadIdx.x];

    // anchor + EPS into registers (a - n + eps == (a+eps) - n)
    const float4* a4 = (const float4*)anchor;
    float4 ae[FULL_K + 1];
    #pragma unroll
    for (int k = 0; k < FULL_K; ++k) {
        float4 a = a4[k * 64 + lane];
        ae[k].x = a.x + EPS;
        ae[k].y = a.y + EPS;
        ae[k].z = a.z + EPS;
        ae[k].w = a.w + EPS;
    }
    if (lane < TAIL_LANES) {
        float4 a = a4[FULL_K * 64 + lane];
        ae[FULL_K].x = a.x + EPS;
        ae[FULL_K].y = a.y + EPS;
        ae[FULL_K].z = a.z + EPS;
        ae[FULL_K].w = a.w + EPS;
    } else {
        ae[FULL_K].x = 0.0f; ae[FULL_K].y = 0.0f;
        ae[FULL_K].z = 0.0f; ae[FULL_K].w = 0.0f;
    }
    __syncthreads();

    const int waves_per_block = blockDim.x >> 6;        // 4
    const int stride = gridDim.x * waves_per_block;
    float local = 0.0f;

    for (int row = blockIdx.x * waves_per_block + wave; row < n_rows; row += stride) {
        const float4* nr = (const float4*)(neg + (size_t)row * DIM);
        float ax = 0.0f, ay = 0.0f, az = 0.0f, aw = 0.0f;
        #pragma unroll
        for (int k = 0; k < FULL_K; ++k) {
            float4 b = nr[k * 64 + lane];
            float dx = ae[k].x - b.x;
            float dy = ae[k].y - b.y;
            float dz = ae[k].z - b.z;
            float dw = ae[k].w - b.w;
            ax = fmaf(dx, dx, ax);
            ay = fmaf(dy, dy, ay);
            az = fmaf(dz, dz, az);
            aw = fmaf(dw, dw, aw);
        }
        if (lane < TAIL_LANES) {
            float4 b = nr[FULL_K * 64 + lane];
            float dx = ae[FULL_K].x - b.x;
            float dy = ae[FULL_K].y - b.y;
            float dz = ae[FULL_K].z - b.z;
            float dw = ae[FULL_K].w - b.w;
            ax = fmaf(dx, dx, ax);
            ay = fmaf(dy, dy, ay);
            az = fmaf(dz, dz, az);
            aw = fmaf(dw, dw, aw);
        }
        float acc = (ax + ay) + (az + aw);
        #pragma unroll
        for (int off = 32; off > 0; off >>= 1)
            acc += __shfl_down(acc, off, 64);
        if (lane == 0) {
            float t = s_dap[row % NPOS] - sqrtf(acc) + MARGIN;
            local += fmaxf(t, 0.0f);
        }
    }

    if (lane == 0) s_partial[wave] = local;
    __syncthreads();
    if (threadIdx.x == 0) {
        float blocksum = 0.0f;
        for (int w = 0; w < waves_per_block; ++w) blocksum += s_partial[w];
        atomicAdd(out, blocksum);
    }
}

extern "C" void kernel_launch(void* const* d_in, const int* in_sizes, int n_in,
                              void* d_out, int out_size, void* d_ws, size_t ws_size,
                              hipStream_t stream) {
    const float* anchor = (const float*)d_in[0];
    const float* pos    = (const float*)d_in[1];
    const float* neg    = (const float*)d_in[2];
    float* out = (float*)d_out;
    float* dap = (float*)d_ws;                  // 5 floats of scratch

    const int n_neg  = in_sizes[2] / DIM;       // 50000
    const int n_rows = (n_neg / NPOS) * NPOS;   // full chunks only

    dap_kernel<<<1, NPOS * 64, 0, stream>>>(anchor, pos, dap, out);

    const int block = 256;
    const int waves_per_block = block / 64;
    int grid = 2048;
    int max_grid = (n_rows + waves_per_block - 1) / waves_per_block;
    if (grid > max_grid) grid = max_grid;
    triplet_kernel<<<grid, block, 0, stream>>>(anchor, neg, dap, out, n_rows);
}